// Round 10
// baseline (340.835 us; speedup 1.0000x reference)
//
#include <hip/hip_runtime.h>

#define H_DIM 768
#define C_DIM 512
#define L_DIM 256
#define S_DIM 2048
#define B_DIM 16

#define IA_STRIDE 520   // 512 + 8: lane stride 1040B = 260 dw = 4 mod 32 banks
#define ATTN_STRIDE 264 // 256 + 8: lane stride 528B = 132 dw = 4 mod 32 banks

typedef __attribute__((ext_vector_type(8))) short short8;
typedef __attribute__((ext_vector_type(4))) float f32x4;
typedef __attribute__((ext_vector_type(2))) __fp16 half2v;   // cvt_pkrtz return type

#define MFMA_F16(a, b, c) __builtin_amdgcn_mfma_f32_16x16x32_f16((a), (b), (c), 0, 0, 0)

__device__ __forceinline__ unsigned short f2h(float f) {
    _Float16 h = (_Float16)f;
    return __builtin_bit_cast(unsigned short, h);
}
__device__ __forceinline__ float h2f(unsigned short u) {
    _Float16 h = __builtin_bit_cast(_Float16, u);
    return (float)h;
}
__device__ __forceinline__ float sigmoid_f(float x) { return 1.0f / (1.0f + __expf(-x)); }

__device__ __forceinline__ short8 cvt8(const float* p) {
    const float4* q = (const float4*)(const void*)p;
    float4 u = q[0], v = q[1];
    half2v h0 = __builtin_amdgcn_cvt_pkrtz(u.x, u.y);
    half2v h1 = __builtin_amdgcn_cvt_pkrtz(u.z, u.w);
    half2v h2 = __builtin_amdgcn_cvt_pkrtz(v.x, v.y);
    half2v h3 = __builtin_amdgcn_cvt_pkrtz(v.z, v.w);
    int4 pk = { __builtin_bit_cast(int, h0), __builtin_bit_cast(int, h1),
                __builtin_bit_cast(int, h2), __builtin_bit_cast(int, h3) };
    return __builtin_bit_cast(short8, pk);
}

// ---------------------------------------------------------------------------
// Frag layouts (one wave frag load = 64 lanes x 16 B = 1 KB contiguous):
//   B operand M[n][k]: lane = (n&15) | (((k>>3)&3)<<4), j = k&7
//     W  (n 32 ct, k 24 kt): frag = ((ct>>3)*24 + kt)*8 + (ct&7)
//     la (n 16 lt, k 16 kt): frag = ((lt>>2)*16 + kt)*4 + (lt&3)
//     lt (n 32 ct, k  8 kt): frag = ((ct>>3)*8  + kt)*8 + (ct&7)
//   A operand x[m][k]: lane = (m&15) | (((k>>3)&3)<<4), j = k&7
//     x  (m 2048 mt, k 24 kt): frag = mt*24 + kt
// ---------------------------------------------------------------------------

// Kernel 0: ONE launch. Label GEMM (128 blocks, latency-bound, hides under
// the streaming blocks) + x repack (nx=2048 slab blocks, COALESCED reads:
// each block owns one 16-row x slab = 48 KB contiguous; scatter only on the
// posted writes) + Wi/Wia repack (64 slab blocks) + fusion zero (1).
__global__ __launch_bounds__(256) void prep_all(
    const float* __restrict__ x,
    const float* __restrict__ Wi, const float* __restrict__ Wia,
    const float* __restrict__ lab,
    const float* __restrict__ Wl,  const float* __restrict__ bl,
    const float* __restrict__ Wla, const float* __restrict__ bla,
    const float* __restrict__ ctx,
    unsigned short* __restrict__ x_f,
    unsigned short* __restrict__ Wi_f, unsigned short* __restrict__ Wia_f,
    unsigned short* __restrict__ la_f, unsigned short* __restrict__ lt_f,
    float* __restrict__ fusion, int nx)
{
    int bid = blockIdx.x;
    if (bid < 128) {    // ---- label-side joint MFMA GEMM (f32 W, cvt8) ----
        const int tid  = threadIdx.x;
        const int wave = tid >> 6;
        const int lane = tid & 63;
        const int quad = lane >> 4;
        const int c16  = lane & 15;
        const int ct2  = bid & 7;
        const int mh   = bid >> 3;           // 0..15
        const int n0   = (ct2 * 4 + wave) * 16;
        const int l0   = mh * 16;

        const f32x4 z4 = {0.f, 0.f, 0.f, 0.f};
        f32x4 a1 = z4, a2 = z4;
        const float* lb  = lab + (size_t)(l0 + c16) * H_DIM + quad * 8;
        const float* wl  = Wl  + (size_t)(n0 + c16) * H_DIM + quad * 8;
        const float* wla = Wla + (size_t)(n0 + c16) * H_DIM + quad * 8;
        for (int kt = 0; kt < 24; ++kt) {
            short8 b1 = cvt8(wl + kt * 32);
            short8 b2 = cvt8(wla + kt * 32);
            short8 a  = cvt8(lb + kt * 32);
            a1 = MFMA_F16(a, b1, a1);
            a2 = MFMA_F16(a, b2, a2);
        }
        const int c = n0 + c16;
        const float blv = bl[c], blav = bla[c], cv = ctx[c];
#pragma unroll
        for (int r = 0; r < 4; ++r) {
            const int l = l0 + quad * 4 + r;
            const float ltv = sigmoid_f(a1[r] + blv);
            const float lav = sigmoid_f(a2[r] + blav) * cv;
            {   // lt_f: n=c, k=l
                const int ctc = c >> 4, ktl = l >> 5;
                const int frag = ((ctc >> 3) * 8 + ktl) * 8 + (ctc & 7);
                const int ln = (c & 15) | (((l >> 3) & 3) << 4);
                lt_f[((size_t)frag * 64 + ln) * 8 + (l & 7)] = f2h(ltv);
            }
            {   // la_f: n=l, k=c
                const int lt = l >> 4, ktc = c >> 5;
                const int frag = ((lt >> 2) * 16 + ktc) * 4 + (lt & 3);
                const int ln = (l & 15) | (((c >> 3) & 3) << 4);
                la_f[((size_t)frag * 64 + ln) * 8 + (c & 7)] = f2h(lav);
            }
        }
        return;
    }
    bid -= 128;
    if (bid < nx) {     // ---- x repack: slab-coalesced, block = mt ----
        const int mt = bid;
        const float* src = x + (size_t)mt * 16 * H_DIM;      // 48 KB contiguous
        unsigned short* dstb = x_f + (size_t)mt * 24 * 512;  // 24 frags x 512 f16
#pragma unroll
        for (int it = 0; it < 6; ++it) {
            const int idx = it * 256 + threadIdx.x;          // 0..1535
            const int o   = idx * 8;                         // f32 offset in slab
            const int row = idx / 96;                        // 0..15  (o/768)
            const int col = o - row * H_DIM;
            short8 v = cvt8(src + o);                        // coalesced read
            const int kt = col >> 5;
            const int ln = row | (((col >> 3) & 3) << 4);
            *(short8*)(void*)(dstb + ((size_t)kt * 64 + ln) * 8) = v;
        }
        return;
    }
    bid -= nx;
    if (bid < 64) {     // ---- Wi/Wia repack: slab-coalesced, block = (m,ct) ----
        const int m  = bid >> 5;
        const int ct = bid & 31;
        const float* src = (m == 0 ? Wi : Wia) + (size_t)ct * 16 * H_DIM;
        unsigned short* dst = (m == 0 ? Wi_f : Wia_f);
#pragma unroll
        for (int it = 0; it < 6; ++it) {
            const int idx = it * 256 + threadIdx.x;
            const int o   = idx * 8;
            const int row = idx / 96;                        // 0..15
            const int col = o - row * H_DIM;
            short8 v = cvt8(src + o);
            const int kt = col >> 5;
            const int frag = ((ct >> 3) * 24 + kt) * 8 + (ct & 7);
            const int ln = row | (((col >> 3) & 3) << 4);
            *(short8*)(void*)(dst + ((size_t)frag * 64 + ln) * 8) = v;
        }
        return;
    }
    // ---- fusion zero ----
    for (int i = threadIdx.x; i < B_DIM * C_DIM; i += 256) fusion[i] = 0.f;
}

// ---------------------------------------------------------------------------
// Kernel 1: fused main — VERBATIM R7/R9 structure (148 us, no spills).
// One block = 32 rows, 256 threads (4 waves), (256,4) -> 4 blocks/CU.
// ---------------------------------------------------------------------------
template<bool XF>
__global__ __launch_bounds__(256, 4) void fused_main(
    const unsigned short* __restrict__ x_f,     // A-frag f16 (XF only)
    const float* __restrict__ x,                // f32 (fallback only)
    const float* __restrict__ bi,
    const float* __restrict__ bia,
    const unsigned short* __restrict__ Wi_f,
    const unsigned short* __restrict__ Wia_f,
    const unsigned short* __restrict__ lt_f,
    const unsigned short* __restrict__ la_f,
    float* __restrict__ fusion)                 // f32 [B][C]
{
    __shared__ unsigned short lds_buf[32 * IA_STRIDE]; // ia / attn(head) / wgt
    __shared__ float rowscratch[4 * 32];
    __shared__ float inv_lds[32];

    const int tid  = threadIdx.x;
    const int wave = tid >> 6;
    const int lane = tid & 63;
    const int quad = lane >> 4;
    const int c16  = lane & 15;

    const int row0 = blockIdx.x * 32;
    const int b    = row0 >> 11;   // / 2048

    const f32x4 z4 = {0.f, 0.f, 0.f, 0.f};
    const int n0 = wave * 128;     // C-column split

    const float*  xb  = x + (size_t)(row0 + c16) * H_DIM + quad * 8;
    const short8* xf8 = (const short8*)(const void*)x_f + ((size_t)blockIdx.x * 2 * 24) * 64 + lane;

    // ========== Phase 1: ia = x@Wia^T (K=768), sigmoid -> LDS =============
    {
        f32x4 acc[2][8];
#pragma unroll
        for (int mt = 0; mt < 2; ++mt)
#pragma unroll
            for (int nt = 0; nt < 8; ++nt) acc[mt][nt] = z4;
        const short8* wa8 = (const short8*)(const void*)Wia_f + (size_t)wave * 192 * 64 + lane;
        for (int kt = 0; kt < 24; ++kt) {
            short8 a0, a1;
            if constexpr (XF) { a0 = xf8[kt * 64]; a1 = xf8[(24 + kt) * 64]; }
            else { a0 = cvt8(xb + kt * 32); a1 = cvt8(xb + 16 * H_DIM + kt * 32); }
#pragma unroll
            for (int nt = 0; nt < 8; ++nt) {
                short8 ba = wa8[(kt * 8 + nt) * 64];
                acc[0][nt] = MFMA_F16(a0, ba, acc[0][nt]);
                acc[1][nt] = MFMA_F16(a1, ba, acc[1][nt]);
            }
        }
#pragma unroll
        for (int nt = 0; nt < 8; ++nt) {
            const int col = n0 + nt * 16 + c16;
            const float bv = bia[col];
#pragma unroll
            for (int mt = 0; mt < 2; ++mt)
#pragma unroll
                for (int r = 0; r < 4; ++r) {
                    const int row = mt * 16 + quad * 4 + r;
                    lds_buf[row * IA_STRIDE + col] = f2h(sigmoid_f(acc[mt][nt][r] + bv));
                }
        }
    }
    __syncthreads();

    // ========== Phase 2: logits = ia @ la^T (K=512) =======================
    const int n0l = wave * 64;   // L-column split
    f32x4 accl[2][4];
#pragma unroll
    for (int mt = 0; mt < 2; ++mt)
#pragma unroll
        for (int nt = 0; nt < 4; ++nt) accl[mt][nt] = z4;
    {
        const unsigned short* ab = lds_buf + c16 * IA_STRIDE + quad * 8;
        const short8* la8 = (const short8*)(const void*)la_f + (size_t)wave * 64 * 64 + lane;
        for (int kt = 0; kt < 16; ++kt) {
            const int kk = kt * 32;
            short8 a0 = *(const short8*)(const void*)(ab + kk);
            short8 a1 = *(const short8*)(const void*)(ab + 16 * IA_STRIDE + kk);
#pragma unroll
            for (int nt = 0; nt < 4; ++nt) {
                short8 bfr = la8[(kt * 4 + nt) * 64];
                accl[0][nt] = MFMA_F16(a0, bfr, accl[0][nt]);
                accl[1][nt] = MFMA_F16(a1, bfr, accl[1][nt]);
            }
        }
    }
    __syncthreads();   // all ia reads complete; lds_buf reusable

    // ========== Phase 3: softmax over L (unnormalized; keep 1/sum) ========
    float rmax[2][4];
#pragma unroll
    for (int mt = 0; mt < 2; ++mt)
#pragma unroll
        for (int r = 0; r < 4; ++r) {
            float m = accl[mt][0][r];
#pragma unroll
            for (int nt = 1; nt < 4; ++nt) m = fmaxf(m, accl[mt][nt][r]);
#pragma unroll
            for (int off = 1; off < 16; off <<= 1) m = fmaxf(m, __shfl_xor(m, off, 64));
            rmax[mt][r] = m;
        }
    if (c16 == 0) {
#pragma unroll
        for (int mt = 0; mt < 2; ++mt)
#pragma unroll
            for (int r = 0; r < 4; ++r)
                rowscratch[wave * 32 + mt * 16 + quad * 4 + r] = rmax[mt][r];
    }
    __syncthreads();
    float rsum[2][4];
#pragma unroll
    for (int mt = 0; mt < 2; ++mt)
#pragma unroll
        for (int r = 0; r < 4; ++r) {
            const int row = mt * 16 + quad * 4 + r;
            float gm = rowscratch[row];
#pragma unroll
            for (int w = 1; w < 4; ++w) gm = fmaxf(gm, rowscratch[w * 32 + row]);
            float s = 0.f;
#pragma unroll
            for (int nt = 0; nt < 4; ++nt) {
                float e = __expf(accl[mt][nt][r] - gm);
                accl[mt][nt][r] = e;
                s += e;
            }
#pragma unroll
            for (int off = 1; off < 16; off <<= 1) s += __shfl_xor(s, off, 64);
            rsum[mt][r] = s;
        }
    __syncthreads();   // maxima consumed
    if (c16 == 0) {
#pragma unroll
        for (int mt = 0; mt < 2; ++mt)
#pragma unroll
            for (int r = 0; r < 4; ++r)
                rowscratch[wave * 32 + mt * 16 + quad * 4 + r] = rsum[mt][r];
    }
    __syncthreads();
#pragma unroll
    for (int mt = 0; mt < 2; ++mt)
#pragma unroll
        for (int r = 0; r < 4; ++r) {
            const int row = mt * 16 + quad * 4 + r;
            const float st = rowscratch[row] + rowscratch[32 + row]
                           + rowscratch[64 + row] + rowscratch[96 + row];
            if (wave == 0 && c16 == 0) inv_lds[row] = 1.0f / st;
#pragma unroll
            for (int nt = 0; nt < 4; ++nt)
                lds_buf[row * ATTN_STRIDE + n0l + nt * 16 + c16] = f2h(accl[mt][nt][r]);
        }
    __syncthreads();

    // ========== Phase 4: weighted = attn @ lt (K=256) =====================
    f32x4 accw[2][8];
#pragma unroll
    for (int mt = 0; mt < 2; ++mt)
#pragma unroll
        for (int nt = 0; nt < 8; ++nt) accw[mt][nt] = z4;
    {
        const unsigned short* ab = lds_buf + c16 * ATTN_STRIDE + quad * 8;
        const short8* lt8 = (const short8*)(const void*)lt_f + (size_t)wave * 64 * 64 + lane;
        for (int kt = 0; kt < 8; ++kt) {
            const int kk = kt * 32;
            short8 a0 = *(const short8*)(const void*)(ab + kk);
            short8 a1 = *(const short8*)(const void*)(ab + 16 * ATTN_STRIDE + kk);
#pragma unroll
            for (int nt = 0; nt < 8; ++nt) {
                short8 bfr = lt8[(kt * 8 + nt) * 64];
                accw[0][nt] = MFMA_F16(a0, bfr, accw[0][nt]);
                accw[1][nt] = MFMA_F16(a1, bfr, accw[1][nt]);
            }
        }
    }
    __syncthreads();   // all attn reads complete; lds_buf reusable for wgt

    // spill wgt = weighted * invsum to LDS (f16); wave-private region
    {
        float invr[2][4];
#pragma unroll
        for (int mt = 0; mt < 2; ++mt)
#pragma unroll
            for (int r = 0; r < 4; ++r) invr[mt][r] = inv_lds[mt * 16 + quad * 4 + r];
#pragma unroll
        for (int nt = 0; nt < 8; ++nt) {
            const int col = n0 + nt * 16 + c16;
#pragma unroll
            for (int mt = 0; mt < 2; ++mt)
#pragma unroll
                for (int r = 0; r < 4; ++r) {
                    const int row = mt * 16 + quad * 4 + r;
                    lds_buf[row * IA_STRIDE + col] = f2h(accw[mt][nt][r] * invr[mt][r]);
                }
        }
    }
    // no barrier: phase 5 reads only this wave's own cols/rows

    // ========== Phase 5: it = x@Wi^T (recompute), fusion + atomics ========
    {
        f32x4 acc[2][8];
#pragma unroll
        for (int mt = 0; mt < 2; ++mt)
#pragma unroll
            for (int nt = 0; nt < 8; ++nt) acc[mt][nt] = z4;
        const short8* wi8 = (const short8*)(const void*)Wi_f + (size_t)wave * 192 * 64 + lane;
        for (int kt = 0; kt < 24; ++kt) {
            short8 a0, a1;
            if constexpr (XF) { a0 = xf8[kt * 64]; a1 = xf8[(24 + kt) * 64]; }
            else { a0 = cvt8(xb + kt * 32); a1 = cvt8(xb + 16 * H_DIM + kt * 32); }
#pragma unroll
            for (int nt = 0; nt < 8; ++nt) {
                short8 bw = wi8[(kt * 8 + nt) * 64];
                acc[0][nt] = MFMA_F16(a0, bw, acc[0][nt]);
                acc[1][nt] = MFMA_F16(a1, bw, acc[1][nt]);
            }
        }
#pragma unroll
        for (int nt = 0; nt < 8; ++nt) {
            const int col = n0 + nt * 16 + c16;
            const float bv = bi[col];
            float s = 0.f;
#pragma unroll
            for (int mt = 0; mt < 2; ++mt)
#pragma unroll
                for (int r = 0; r < 4; ++r) {
                    const int row = mt * 16 + quad * 4 + r;
                    s += h2f(lds_buf[row * IA_STRIDE + col]) * sigmoid_f(acc[mt][nt][r] + bv);
                }
            s += __shfl_xor(s, 16, 64);
            s += __shfl_xor(s, 32, 64);
            if (lane < 16) atomicAdd(&fusion[b * C_DIM + col], s);
        }
    }
}

// ---------------------------------------------------------------------------
// Kernel 2: out[b][h] = sum_c fusion[b][c] * Wp[h][c]. 8 lanes per row.
// ---------------------------------------------------------------------------
__global__ __launch_bounds__(256) void out_kernel(
    const float* __restrict__ fusion,
    const float* __restrict__ Wp,
    float* __restrict__ out)
{
    const int idx = blockIdx.x * 256 + threadIdx.x;
    const int R   = idx >> 3;
    const int sub = idx & 7;
    const int bb  = R / H_DIM;
    const int h   = R - bb * H_DIM;
    const float* wp = Wp + (size_t)h * C_DIM;
    const float* f  = fusion + bb * C_DIM;
    float s = 0.f;
#pragma unroll
    for (int j = 0; j < 16; ++j) {
        const int c = j * 32 + sub * 4;
        float4 wv = *(const float4*)(const void*)(wp + c);
        float4 fv = *(const float4*)(const void*)(f + c);
        s += fv.x * wv.x + fv.y * wv.y + fv.z * wv.z + fv.w * wv.w;
    }
    s += __shfl_xor(s, 1, 64);
    s += __shfl_xor(s, 2, 64);
    s += __shfl_xor(s, 4, 64);
    if (sub == 0) out[R] = s;
}

extern "C" void kernel_launch(void* const* d_in, const int* in_sizes, int n_in,
                              void* d_out, int out_size, void* d_ws, size_t ws_size,
                              hipStream_t stream)
{
    const float* x    = (const float*)d_in[0];
    const float* lab  = (const float*)d_in[1];
    const float* Wi   = (const float*)d_in[2];
    const float* bi   = (const float*)d_in[3];
    const float* Wl   = (const float*)d_in[4];
    const float* bl   = (const float*)d_in[5];
    const float* Wia  = (const float*)d_in[6];
    const float* bia  = (const float*)d_in[7];
    const float* Wla  = (const float*)d_in[8];
    const float* bla  = (const float*)d_in[9];
    const float* ctx  = (const float*)d_in[10];
    const float* Wp   = (const float*)d_in[11];

    char* ws = (char*)d_ws;
    unsigned short* Wi_f  = (unsigned short*)(ws);               // 768 KB
    unsigned short* Wia_f = (unsigned short*)(ws + 786432);      // 768 KB
    unsigned short* la_f  = (unsigned short*)(ws + 1572864);     // 256 KB
    unsigned short* lt_f  = (unsigned short*)(ws + 1835008);     // 256 KB
    float* fusion         = (float*)(ws + 2097152);              // 32 KB
    unsigned short* x_f   = (unsigned short*)(ws + 2129920);     // 48 MB (optional)
    const size_t NEED_XF  = 2129920 + (size_t)32768 * 768 * 2;   // ~50.5 MB

    const bool xf = (ws_size >= NEED_XF);
    const int nx = xf ? 2048 : 0;    // one block per 16-row x slab
    prep_all<<<128 + nx + 64 + 1, 256, 0, stream>>>(
        x, Wi, Wia, lab, Wl, bl, Wla, bla, ctx,
        x_f, Wi_f, Wia_f, la_f, lt_f, fusion, nx);
    if (xf) {
        fused_main<true><<<(B_DIM * S_DIM) / 32, 256, 0, stream>>>(
            x_f, x, bi, bia, Wi_f, Wia_f, lt_f, la_f, fusion);
    } else {
        fused_main<false><<<(B_DIM * S_DIM) / 32, 256, 0, stream>>>(
            nullptr, x, bi, bia, Wi_f, Wia_f, lt_f, la_f, fusion);
    }
    out_kernel<<<384, 256, 0, stream>>>(fusion, Wp, (float*)d_out);
}